// Round 8
// baseline (250.085 us; speedup 1.0000x reference)
//
#include <hip/hip_runtime.h>
#include <hip/hip_bf16.h>

// IndRNNv2: 2 layers of { lin = x @ w^T + b ; h_s = relu(lin_s + r*h_{s-1}) }
// SEQ=256, BATCH=32, IN=HID=1024.
//
// bf16 hi/lo split GEMM on MFMA, 3 terms: C = Ahi*Bhi + Alo*Bhi + Ahi*Blo.
// Compact storage [hi | lo] (K=2048 physical) for both operands.
//
// R7->R8: GEMM model pinned by R4/R5: t = staged_bytes / staging_BW, and
// staging BW scales with blocks/CU (2/CU -> 35 GB/s/CU; 4/CU -> ~55, m97@4k).
// R4's split-K regression was its +50% staged bytes (pre-merge), not split-K.
// So: split-K x2 WITH the term-merged loop = same 524 MB staged, 4 blocks/CU.
// Partial reduce fused into scans (R4-proven), dual-stream pipelined NB=16.

#define SEQ   256
#define BATCH 32
#define M_    (SEQ*BATCH)   // 8192
#define K_    1024
#define KC    2048          // compact split K (hi | lo)
#define N_    1024

typedef __attribute__((ext_vector_type(8))) short  short8;
typedef __attribute__((ext_vector_type(4))) float  floatx4;

// ---------------- fused f32 -> [hi | lo] bf16 split (x, w0, w1) -------------
// grid: [0,8192) -> x, [8192,9216) -> w0, [9216,10240) -> w1
__global__ __launch_bounds__(256) void split_all_k(
    const float* __restrict__ x,  __hip_bfloat16* __restrict__ dx,
    const float* __restrict__ w0, __hip_bfloat16* __restrict__ dw0,
    const float* __restrict__ w1, __hip_bfloat16* __restrict__ dw1)
{
    int bid = blockIdx.x;
    const float* src;
    __hip_bfloat16* dst;
    int t;
    if (bid < 8192)      { src = x;  dst = dx;  t = bid * 256 + threadIdx.x; }
    else if (bid < 9216) { src = w0; dst = dw0; t = (bid - 8192) * 256 + threadIdx.x; }
    else                 { src = w1; dst = dw1; t = (bid - 9216) * 256 + threadIdx.x; }

    int idx = t << 2;                       // 4 f32 per thread
    int row = idx >> 10, col = idx & 1023;  // source rows of 1024
    const float4 v = *reinterpret_cast<const float4*>(src + idx);
    float f[4] = {v.x, v.y, v.z, v.w};
    __hip_bfloat16 hi[4], lo[4];
#pragma unroll
    for (int i = 0; i < 4; ++i) {
        hi[i] = __float2bfloat16(f[i]);
        lo[i] = __float2bfloat16(f[i] - __bfloat162float(hi[i]));
    }
    size_t base = (size_t)row * KC + col;
    *reinterpret_cast<uint2*>(dst + base)        = *reinterpret_cast<const uint2*>(hi);
    *reinterpret_cast<uint2*>(dst + base + 1024) = *reinterpret_cast<const uint2*>(lo);
}

// ---------------- GEMM: P[m][n] = sum over 3 split terms ----------------
// 128x128 tile, BK=32, 4 waves (2x2), per step stage 4 tiles (Ahi/Alo/Bhi/Blo,
// 32 KB) then 48 MFMA/wave. 2 barriers per step. XCD M-chunked swizzle.
// NSPLIT=2: h = bid>>9 selects K-half (16 steps) and partial buffer; both
// halves of a tile share an XCD (bid%8 invariant under +512).
#define TM 128
#define TN 128
#define TK 32
#define NXCD 8
#define NTILES 512           // (M_/TM)*(N_/TN) = 64*8

template <int NSPLIT>
__global__ __launch_bounds__(256) void gemm_bt(
    const __hip_bfloat16* __restrict__ A,   // [M_][KC]
    const __hip_bfloat16* __restrict__ B,   // [N_][KC]
    float* __restrict__ P0,                 // [M_][N_] partial (h=0 / full)
    float* __restrict__ P1)                 // [M_][N_] partial (h=1)
{
    __shared__ __hip_bfloat16 Ah[TM * TK];  // 8 KB each, 32 KB total
    __shared__ __hip_bfloat16 Al[TM * TK];
    __shared__ __hip_bfloat16 Bh[TN * TK];
    __shared__ __hip_bfloat16 Bl[TN * TK];

    const int bid  = blockIdx.x;
    const int h    = (NSPLIT == 2) ? (bid >> 9) : 0;
    const int b512 = bid & (NTILES - 1);
    const int xcd  = b512 & (NXCD - 1);
    const int slot = b512 >> 3;
    const int tile = xcd * (NTILES / NXCD) + slot;
    const int ty   = tile >> 3;
    const int tx   = tile & 7;

    const int t    = threadIdx.x;
    const int lane = t & 63;
    const int wv   = t >> 6;
    const int wr   = wv >> 1;
    const int wc   = wv & 1;
    const int m0   = ty * TM;
    const int n0   = tx * TN;
    const int fr   = lane & 15;
    const int kb   = (lane >> 4) << 3;

    floatx4 acc[4][4] = {};

    const int kt0 = h * (K_ / TK / NSPLIT);
    for (int it = 0; it < K_ / TK / NSPLIT; ++it) {   // 16 steps (NSPLIT=2)
        const int kt  = kt0 + it;
        const int hi0 = kt * TK;               // hi cols
        const int lo0 = 1024 + kt * TK;        // lo cols
        __syncthreads();   // prior iteration's ds_reads done before overwrite
#pragma unroll
        for (int i = 0; i < 2; ++i) {
            const int chunk = i * 256 + t;     // 0..511, 16B each
            const int row = chunk >> 2;
            const int c8  = (chunk & 3) << 3;
            const size_t arow = (size_t)(m0 + row) * KC;
            const size_t brow = (size_t)(n0 + row) * KC;
            __builtin_amdgcn_global_load_lds(
                (__attribute__((address_space(1))) void*)(A + arow + hi0 + c8),
                (__attribute__((address_space(3))) void*)(&Ah[chunk * 8]), 16, 0, 0);
            __builtin_amdgcn_global_load_lds(
                (__attribute__((address_space(1))) void*)(A + arow + lo0 + c8),
                (__attribute__((address_space(3))) void*)(&Al[chunk * 8]), 16, 0, 0);
            __builtin_amdgcn_global_load_lds(
                (__attribute__((address_space(1))) void*)(B + brow + hi0 + c8),
                (__attribute__((address_space(3))) void*)(&Bh[chunk * 8]), 16, 0, 0);
            __builtin_amdgcn_global_load_lds(
                (__attribute__((address_space(1))) void*)(B + brow + lo0 + c8),
                (__attribute__((address_space(3))) void*)(&Bl[chunk * 8]), 16, 0, 0);
        }
        __syncthreads();   // compiler drains vmcnt before barrier

        short8 afh[4], afl[4], bfh[4], bfl[4];
#pragma unroll
        for (int i = 0; i < 4; ++i) {
            const int ar = (wr * 64 + i * 16 + fr) * TK + kb;
            afh[i] = *reinterpret_cast<const short8*>(&Ah[ar]);
            afl[i] = *reinterpret_cast<const short8*>(&Al[ar]);
        }
#pragma unroll
        for (int j = 0; j < 4; ++j) {
            const int br = (wc * 64 + j * 16 + fr) * TK + kb;
            bfh[j] = *reinterpret_cast<const short8*>(&Bh[br]);
            bfl[j] = *reinterpret_cast<const short8*>(&Bl[br]);
        }
#pragma unroll
        for (int i = 0; i < 4; ++i)
#pragma unroll
            for (int j = 0; j < 4; ++j) {
                acc[i][j] = __builtin_amdgcn_mfma_f32_16x16x32_bf16(afh[i], bfh[j], acc[i][j], 0, 0, 0);
                acc[i][j] = __builtin_amdgcn_mfma_f32_16x16x32_bf16(afl[i], bfh[j], acc[i][j], 0, 0, 0);
                acc[i][j] = __builtin_amdgcn_mfma_f32_16x16x32_bf16(afh[i], bfl[j], acc[i][j], 0, 0, 0);
            }
    }

    float* __restrict__ P = (h == 0) ? P0 : P1;
    // epilogue: C/D layout (16x16): col = lane&15, row = (lane>>4)*4 + reg
#pragma unroll
    for (int j = 0; j < 4; ++j) {
        const int col = n0 + wc * 64 + j * 16 + fr;
#pragma unroll
        for (int i = 0; i < 4; ++i) {
            const int row = m0 + wr * 64 + i * 16 + ((lane >> 4) << 2);
#pragma unroll
            for (int jj = 0; jj < 4; ++jj)
                P[(size_t)(row + jj) * N_ + col] = acc[i][j][jj];
        }
    }
}

// ---------------- sequential scan over S (fused split-K reduce + bias) ------
// Dual-stream software pipeline: prefetch next NB-step batch of p0 (and p1)
// while processing the current. l = p0 + p1 + bias.
// LAYER==0: emit compact [hi|lo] split acts + h0T. LAYER==1: y1 in place + h1T.
#define NB 16

template <int LAYER, bool SPLIT2>
__global__ __launch_bounds__(64) void scan_k(
    float* lin,                              // [SEQ][BATCH][N_] p0; LAYER==1: also output
    const float* __restrict__ p1,            // [SEQ][BATCH][N_] (SPLIT2)
    const float* __restrict__ bias,          // [N_]
    const float* __restrict__ rec,           // [2][N_]
    __hip_bfloat16* __restrict__ asplit,     // LAYER==0: [M_][KC]
    float* __restrict__ hT)                  // [BATCH][2*N_]
{
    const int tid = blockIdx.x * 64 + threadIdx.x;   // 0..32767
    const int b = tid >> 10, n = tid & 1023;
    const float r  = rec[LAYER * N_ + n];
    const float bj = bias[n];
    float h = 0.f;

    float v[NB], vn[NB], u[NB], un[NB];
#pragma unroll
    for (int j = 0; j < NB; ++j) {
        v[j] = lin[(size_t)j * (BATCH * N_) + tid];
        if (SPLIT2) u[j] = p1[(size_t)j * (BATCH * N_) + tid];
    }

    for (int sb = 0; sb < SEQ / NB; ++sb) {
        const int sbase = sb * NB;
        if (sb + 1 < SEQ / NB) {
#pragma unroll
            for (int j = 0; j < NB; ++j) {
                vn[j] = lin[(size_t)(sbase + NB + j) * (BATCH * N_) + tid];
                if (SPLIT2) un[j] = p1[(size_t)(sbase + NB + j) * (BATCH * N_) + tid];
            }
        }
#pragma unroll
        for (int j = 0; j < NB; ++j) {
            float l = v[j] + bj;
            if (SPLIT2) l += u[j];
            h = fmaxf(fmaf(r, h, l), 0.f);
            if (LAYER == 0) {
                const size_t base = (size_t)((sbase + j) * BATCH + b) * KC + n;
                __hip_bfloat16 hi = __float2bfloat16(h);
                __hip_bfloat16 lo = __float2bfloat16(h - __bfloat162float(hi));
                asplit[base]        = hi;   // compact [hi | lo]
                asplit[base + 1024] = lo;
            } else {
                lin[(size_t)(sbase + j) * (BATCH * N_) + tid] = h;
            }
        }
#pragma unroll
        for (int j = 0; j < NB; ++j) {
            v[j] = vn[j];
            if (SPLIT2) u[j] = un[j];
        }
    }
    hT[(size_t)b * (2 * N_) + LAYER * N_ + n] = h;
}

// ---------------- launch ----------------
extern "C" void kernel_launch(void* const* d_in, const int* in_sizes, int n_in,
                              void* d_out, int out_size, void* d_ws, size_t ws_size,
                              hipStream_t stream)
{
    const float* x   = (const float*)d_in[0];
    const float* w0  = (const float*)d_in[1];
    const float* b0  = (const float*)d_in[2];
    const float* w1  = (const float*)d_in[3];
    const float* b1  = (const float*)d_in[4];
    const float* rec = (const float*)d_in[5];

    float* out = (float*)d_out;
    float* y   = out;                               // [SEQ][BATCH][N_] — P0 scratch then final y1
    float* hT  = out + (size_t)SEQ * BATCH * N_;    // [BATCH][2*N_]

    // ws layout: A0 33.55 MB | W0 4.19 | W1 4.19 | P1 33.55 (f32) = 75.5 MB
    // (R4 ran this exact deep layout successfully -> ws_size >= 75.5 MB proven)
    __hip_bfloat16* A0 = (__hip_bfloat16*)d_ws;
    __hip_bfloat16* W0 = A0 + (size_t)M_ * KC;
    __hip_bfloat16* W1 = W0 + (size_t)N_ * KC;
    float*          P1 = (float*)(W1 + (size_t)N_ * KC);
    const size_t need = (size_t)M_ * KC * 2 + 2 * (size_t)N_ * KC * 2
                      + (size_t)M_ * N_ * 4;        // 75,497,472 B
    const bool deep = ws_size >= need;

    // 1. split x, w0, w1 -> compact [hi|lo] bf16 (one kernel)
    split_all_k<<<10240, 256, 0, stream>>>(x, A0, w0, W0, w1, W1);

    if (deep) {
        // 2. lin0 partials (4 blocks/CU)
        gemm_bt<2><<<2 * NTILES, 256, 0, stream>>>(A0, W0, y, P1);
        // 3. scan layer 0 (reduce p0+p1+b0) -> compact split acts + h0T
        scan_k<0, true><<<(BATCH * N_) / 64, 64, 0, stream>>>(y, P1, b0, rec, A0, hT);
        // 4. lin1 partials
        gemm_bt<2><<<2 * NTILES, 256, 0, stream>>>(A0, W1, y, P1);
        // 5. scan layer 1 -> y1 (in place) + h1T
        scan_k<1, true><<<(BATCH * N_) / 64, 64, 0, stream>>>(y, P1, b1, rec, nullptr, hT);
    } else {
        gemm_bt<1><<<NTILES, 256, 0, stream>>>(A0, W0, y, nullptr);
        scan_k<0, false><<<(BATCH * N_) / 64, 64, 0, stream>>>(y, nullptr, b0, rec, A0, hT);
        gemm_bt<1><<<NTILES, 256, 0, stream>>>(A0, W1, y, nullptr);
        scan_k<1, false><<<(BATCH * N_) / 64, 64, 0, stream>>>(y, nullptr, b1, rec, nullptr, hT);
    }
}

// Round 9
// 228.368 us; speedup vs baseline: 1.0951x; 1.0951x over previous
//
#include <hip/hip_runtime.h>
#include <hip/hip_bf16.h>

// IndRNNv2: 2 layers of { lin = x @ w^T + b ; h_s = relu(lin_s + r*h_{s-1}) }
// SEQ=256, BATCH=32, IN=HID=1024.
//
// bf16 hi/lo split GEMM on MFMA, 3 terms: C = Ahi*Bhi + Alo*Bhi + Ahi*Blo.
// Compact storage [hi | lo] (K=2048 physical) for both operands.
// GEMM: R5 term-merged single-K kernel (58.6us, 862 TF = the 128^2 2-phase
// structure ceiling). R8's split-K x2 proved staging BW (~8-9 TB/s) is
// blocks/CU-insensitive -> reverted.
//
// R8->R9: scan codegen fix. scan1 was IN-PLACE (read+write same buffer,
// non-restrict) -> compiler cannot hoist the prefetch batch above the
// stores -> loads serialize at full memory latency (both R6/R7 pipeline
// attempts null). Now: gemm1 -> L0 (ws scratch), scan1: L0 -> y (d_out),
// every scan pointer __restrict__ and disjoint, NB=32 (4 MB in flight).

#define SEQ   256
#define BATCH 32
#define M_    (SEQ*BATCH)   // 8192
#define K_    1024
#define KC    2048          // compact split K (hi | lo)
#define N_    1024

typedef __attribute__((ext_vector_type(8))) short  short8;
typedef __attribute__((ext_vector_type(4))) float  floatx4;

// ---------------- fused f32 -> [hi | lo] bf16 split (x, w0, w1) -------------
// grid: [0,8192) -> x, [8192,9216) -> w0, [9216,10240) -> w1
__global__ __launch_bounds__(256) void split_all_k(
    const float* __restrict__ x,  __hip_bfloat16* __restrict__ dx,
    const float* __restrict__ w0, __hip_bfloat16* __restrict__ dw0,
    const float* __restrict__ w1, __hip_bfloat16* __restrict__ dw1)
{
    int bid = blockIdx.x;
    const float* src;
    __hip_bfloat16* dst;
    int t;
    if (bid < 8192)      { src = x;  dst = dx;  t = bid * 256 + threadIdx.x; }
    else if (bid < 9216) { src = w0; dst = dw0; t = (bid - 8192) * 256 + threadIdx.x; }
    else                 { src = w1; dst = dw1; t = (bid - 9216) * 256 + threadIdx.x; }

    int idx = t << 2;                       // 4 f32 per thread
    int row = idx >> 10, col = idx & 1023;  // source rows of 1024
    const float4 v = *reinterpret_cast<const float4*>(src + idx);
    float f[4] = {v.x, v.y, v.z, v.w};
    __hip_bfloat16 hi[4], lo[4];
#pragma unroll
    for (int i = 0; i < 4; ++i) {
        hi[i] = __float2bfloat16(f[i]);
        lo[i] = __float2bfloat16(f[i] - __bfloat162float(hi[i]));
    }
    size_t base = (size_t)row * KC + col;
    *reinterpret_cast<uint2*>(dst + base)        = *reinterpret_cast<const uint2*>(hi);
    *reinterpret_cast<uint2*>(dst + base + 1024) = *reinterpret_cast<const uint2*>(lo);
}

// ---------------- GEMM: P[m][n] = sum over 3 split terms ----------------
// 128x128 tile, BK=32, 4 waves (2x2), per step stage 4 tiles (Ahi/Alo/Bhi/Blo,
// 32 KB) then 48 MFMA/wave (3 terms x 4x4 frags). 2 barriers per step,
// 32 steps. XCD M-chunked swizzle. (Byte-identical to the R5 kernel.)
#define TM 128
#define TN 128
#define TK 32
#define NXCD 8
#define NTILES 512           // (M_/TM)*(N_/TN) = 64*8

__global__ __launch_bounds__(256) void gemm_bt(
    const __hip_bfloat16* __restrict__ A,   // [M_][KC]
    const __hip_bfloat16* __restrict__ B,   // [N_][KC]
    float* __restrict__ P)                  // [M_][N_]
{
    __shared__ __hip_bfloat16 Ah[TM * TK];  // 8 KB each
    __shared__ __hip_bfloat16 Al[TM * TK];
    __shared__ __hip_bfloat16 Bh[TN * TK];
    __shared__ __hip_bfloat16 Bl[TN * TK];

    // XCD M-chunked swizzle: XCD k owns M-panels [8k,8k+8) x all 8 N-panels.
    const int bid  = blockIdx.x;
    const int xcd  = bid & (NXCD - 1);
    const int slot = bid >> 3;
    const int tile = xcd * (NTILES / NXCD) + slot;
    const int ty   = tile >> 3;
    const int tx   = tile & 7;

    const int t    = threadIdx.x;
    const int lane = t & 63;
    const int wv   = t >> 6;
    const int wr   = wv >> 1;
    const int wc   = wv & 1;
    const int m0   = ty * TM;
    const int n0   = tx * TN;
    const int fr   = lane & 15;
    const int kb   = (lane >> 4) << 3;

    floatx4 acc[4][4] = {};

    for (int kt = 0; kt < K_ / TK; ++kt) {     // 32 steps
        const int hi0 = kt * TK;               // hi cols
        const int lo0 = 1024 + kt * TK;        // lo cols
        __syncthreads();   // prior iteration's ds_reads done before overwrite
#pragma unroll
        for (int i = 0; i < 2; ++i) {
            const int chunk = i * 256 + t;     // 0..511, 16B each
            const int row = chunk >> 2;
            const int c8  = (chunk & 3) << 3;
            const size_t arow = (size_t)(m0 + row) * KC;
            const size_t brow = (size_t)(n0 + row) * KC;
            __builtin_amdgcn_global_load_lds(
                (__attribute__((address_space(1))) void*)(A + arow + hi0 + c8),
                (__attribute__((address_space(3))) void*)(&Ah[chunk * 8]), 16, 0, 0);
            __builtin_amdgcn_global_load_lds(
                (__attribute__((address_space(1))) void*)(A + arow + lo0 + c8),
                (__attribute__((address_space(3))) void*)(&Al[chunk * 8]), 16, 0, 0);
            __builtin_amdgcn_global_load_lds(
                (__attribute__((address_space(1))) void*)(B + brow + hi0 + c8),
                (__attribute__((address_space(3))) void*)(&Bh[chunk * 8]), 16, 0, 0);
            __builtin_amdgcn_global_load_lds(
                (__attribute__((address_space(1))) void*)(B + brow + lo0 + c8),
                (__attribute__((address_space(3))) void*)(&Bl[chunk * 8]), 16, 0, 0);
        }
        __syncthreads();   // compiler drains vmcnt before barrier

        short8 afh[4], afl[4], bfh[4], bfl[4];
#pragma unroll
        for (int i = 0; i < 4; ++i) {
            const int ar = (wr * 64 + i * 16 + fr) * TK + kb;
            afh[i] = *reinterpret_cast<const short8*>(&Ah[ar]);
            afl[i] = *reinterpret_cast<const short8*>(&Al[ar]);
        }
#pragma unroll
        for (int j = 0; j < 4; ++j) {
            const int br = (wc * 64 + j * 16 + fr) * TK + kb;
            bfh[j] = *reinterpret_cast<const short8*>(&Bh[br]);
            bfl[j] = *reinterpret_cast<const short8*>(&Bl[br]);
        }
#pragma unroll
        for (int i = 0; i < 4; ++i)
#pragma unroll
            for (int j = 0; j < 4; ++j) {
                acc[i][j] = __builtin_amdgcn_mfma_f32_16x16x32_bf16(afh[i], bfh[j], acc[i][j], 0, 0, 0);
                acc[i][j] = __builtin_amdgcn_mfma_f32_16x16x32_bf16(afl[i], bfh[j], acc[i][j], 0, 0, 0);
                acc[i][j] = __builtin_amdgcn_mfma_f32_16x16x32_bf16(afh[i], bfl[j], acc[i][j], 0, 0, 0);
            }
    }

    // epilogue: C/D layout (16x16): col = lane&15, row = (lane>>4)*4 + reg
#pragma unroll
    for (int j = 0; j < 4; ++j) {
        const int col = n0 + wc * 64 + j * 16 + fr;
#pragma unroll
        for (int i = 0; i < 4; ++i) {
            const int row = m0 + wr * 64 + i * 16 + ((lane >> 4) << 2);
#pragma unroll
            for (int jj = 0; jj < 4; ++jj)
                P[(size_t)(row + jj) * N_ + col] = acc[i][j][jj];
        }
    }
}

// ---------------- sequential scan over S (adds bias) ----------------
// All pointers restrict + disjoint so the NB-batch prefetch is hoistable
// above the compute/store loop (in-place aliasing defeated it in R6/R7).
// LAYER==0: lin -> compact [hi|lo] split acts + h0T.
// LAYER==1: lin -> yout (y1) + h1T.
#define NB 32

template <int LAYER>
__global__ __launch_bounds__(64) void scan_k(
    const float* __restrict__ lin,           // [SEQ][BATCH][N_]
    const float* __restrict__ bias,          // [N_]
    const float* __restrict__ rec,           // [2][N_]
    __hip_bfloat16* __restrict__ asplit,     // LAYER==0: [M_][KC]
    float* __restrict__ yout,                // LAYER==1: [SEQ][BATCH][N_]
    float* __restrict__ hT)                  // [BATCH][2*N_]
{
    const int tid = blockIdx.x * 64 + threadIdx.x;   // 0..32767
    const int b = tid >> 10, n = tid & 1023;
    const float r  = rec[LAYER * N_ + n];
    const float bj = bias[n];
    float h = 0.f;

    float v[NB], vn[NB];
#pragma unroll
    for (int j = 0; j < NB; ++j)
        v[j] = lin[(size_t)j * (BATCH * N_) + tid];

    for (int sb = 0; sb < SEQ / NB; ++sb) {
        const int sbase = sb * NB;
        if (sb + 1 < SEQ / NB) {
#pragma unroll
            for (int j = 0; j < NB; ++j)
                vn[j] = lin[(size_t)(sbase + NB + j) * (BATCH * N_) + tid];
        }
#pragma unroll
        for (int j = 0; j < NB; ++j) {
            h = fmaxf(fmaf(r, h, v[j] + bj), 0.f);
            if (LAYER == 0) {
                const size_t base = (size_t)((sbase + j) * BATCH + b) * KC + n;
                __hip_bfloat16 hi = __float2bfloat16(h);
                __hip_bfloat16 lo = __float2bfloat16(h - __bfloat162float(hi));
                asplit[base]        = hi;   // compact [hi | lo]
                asplit[base + 1024] = lo;
            } else {
                yout[(size_t)(sbase + j) * (BATCH * N_) + tid] = h;
            }
        }
#pragma unroll
        for (int j = 0; j < NB; ++j) v[j] = vn[j];
    }
    hT[(size_t)b * (2 * N_) + LAYER * N_ + n] = h;
}

// ---------------- launch ----------------
extern "C" void kernel_launch(void* const* d_in, const int* in_sizes, int n_in,
                              void* d_out, int out_size, void* d_ws, size_t ws_size,
                              hipStream_t stream)
{
    const float* x   = (const float*)d_in[0];
    const float* w0  = (const float*)d_in[1];
    const float* b0  = (const float*)d_in[2];
    const float* w1  = (const float*)d_in[3];
    const float* b1  = (const float*)d_in[4];
    const float* rec = (const float*)d_in[5];

    float* out = (float*)d_out;
    float* y   = out;                               // [SEQ][BATCH][N_] — final y1 (written by scan1 only)
    float* hT  = out + (size_t)SEQ * BATCH * N_;    // [BATCH][2*N_]

    // ws layout: A0 33.55 MB | W0 4.19 | W1 4.19 | L0 33.55 (f32) = 75.5 MB
    // (R4's deep path ran this size successfully -> ws_size >= 75.5 MB proven)
    __hip_bfloat16* A0 = (__hip_bfloat16*)d_ws;
    __hip_bfloat16* W0 = A0 + (size_t)M_ * KC;
    __hip_bfloat16* W1 = W0 + (size_t)N_ * KC;
    float*          L0 = (float*)(W1 + (size_t)N_ * KC);   // lin scratch [SEQ][BATCH][N_]

    // 1. split x, w0, w1 -> compact [hi|lo] bf16 (one kernel)
    split_all_k<<<10240, 256, 0, stream>>>(x, A0, w0, W0, w1, W1);

    // 2. lin0 = x @ w0^T -> L0   (bias added in scan)
    gemm_bt<<<NTILES, 256, 0, stream>>>(A0, W0, L0);

    // 3. scan layer 0: L0 -> compact split acts (reuse A0) + h0T
    scan_k<0><<<(BATCH * N_) / 64, 64, 0, stream>>>(L0, b0, rec, A0, nullptr, hT);

    // 4. lin1 = y0 @ w1^T -> L0
    gemm_bt<<<NTILES, 256, 0, stream>>>(A0, W1, L0);

    // 5. scan layer 1: L0 -> y1 (d_out) + h1T
    scan_k<1><<<(BATCH * N_) / 64, 64, 0, stream>>>(L0, b1, rec, nullptr, y, hT);
}